// Round 1
// baseline (358.409 us; speedup 1.0000x reference)
//
#include <hip/hip_runtime.h>

// Correlation: out[b, (p+4)*9+(q+4), y, x] = (1/128) * sum_c A[b,c,y,x] * B[b,c,y+p,x+q]
// B zero-padded outside [0,128) in both spatial dims. p,q in [-4,4].
// Shapes: A,B = (8,128,128,128) fp32; out = (8,81,128,128) fp32.

#define CC 8          // channels per LDS chunk
#define BWP 136       // padded B row width (x index j corresponds to x = j-4)

__global__ __launch_bounds__(576, 5)
void corr_kernel(const float* __restrict__ A, const float* __restrict__ B,
                 float* __restrict__ out)
{
    // block -> (batch, y); batch = blockIdx%8 gives XCD affinity (L2 locality for b-row reuse)
    const int bidx = blockIdx.x;
    const int bb = bidx & 7;
    const int y  = bidx >> 3;

    const int tid  = threadIdx.x;
    const int wave = tid >> 6;      // 0..8  -> p = wave-4
    const int lane = tid & 63;
    const int cs   = lane >> 5;     // channel split (0/1)
    const int xt   = lane & 31;     // x-tile, NX=4
    const int x0   = xt << 2;       // x = x0..x0+3

    __shared__ float a_s[CC][128];
    __shared__ float b_s[CC][9][BWP];

    float acc[9][4];
    #pragma unroll
    for (int q = 0; q < 9; ++q)
        #pragma unroll
        for (int i = 0; i < 4; ++i) acc[q][i] = 0.f;

    const long plane = 128L * 128L;
    const float* Abase = A + (long)bb * 128 * plane + (long)y * 128;
    const float* Bbase = B + (long)bb * 128 * plane;

    for (int ch0 = 0; ch0 < 128; ch0 += CC) {
        // ---- stage A chunk: CC rows of 128 floats (32 float4 each)
        if (tid < CC * 32) {
            const int c_l = tid >> 5;
            const int xf  = (tid & 31) << 2;
            const float4 v = *(const float4*)(Abase + (long)(ch0 + c_l) * plane + xf);
            *(float4*)&a_s[c_l][xf] = v;
        }
        // ---- stage B chunk: CC*9 rows of 34 float4 (first/last float4 = zero pad)
        for (int j = tid; j < CC * 9 * 34; j += 576) {
            const int row = j / 34;
            const int f4  = j - row * 34;
            const int c_l = row / 9;
            const int pr  = row - c_l * 9;       // 0..8 -> p = pr-4
            const int ys  = y + pr - 4;
            float4 v = make_float4(0.f, 0.f, 0.f, 0.f);
            if (f4 >= 1 && f4 <= 32 && (unsigned)ys < 128u) {
                v = *(const float4*)(Bbase + (long)(ch0 + c_l) * plane
                                     + (long)ys * 128 + ((f4 - 1) << 2));
            }
            *(float4*)&b_s[c_l][pr][f4 << 2] = v;
        }
        __syncthreads();

        // ---- compute: each lane does channels (2*cc + cs) of this chunk
        #pragma unroll
        for (int cc = 0; cc < CC / 2; ++cc) {
            const int c_l = 2 * cc + cs;
            const float4 av = *(const float4*)&a_s[c_l][x0];
            // b_s index j = x + 4; need x0+i+q, i in 0..3, q in -4..4 -> j in [x0, x0+11]
            const float4 b0 = *(const float4*)&b_s[c_l][wave][x0];
            const float4 b1 = *(const float4*)&b_s[c_l][wave][x0 + 4];
            const float4 b2 = *(const float4*)&b_s[c_l][wave][x0 + 8];
            const float bw[12] = { b0.x, b0.y, b0.z, b0.w,
                                   b1.x, b1.y, b1.z, b1.w,
                                   b2.x, b2.y, b2.z, b2.w };
            const float av4[4] = { av.x, av.y, av.z, av.w };
            #pragma unroll
            for (int q = 0; q < 9; ++q)
                #pragma unroll
                for (int i = 0; i < 4; ++i)
                    acc[q][i] += av4[i] * bw[q + i];
        }
        __syncthreads();
    }

    // ---- combine channel-split halves (lane L += lane L+32)
    #pragma unroll
    for (int q = 0; q < 9; ++q)
        #pragma unroll
        for (int i = 0; i < 4; ++i) {
            const float v = __shfl_down(acc[q][i], 32);
            acc[q][i] += v;
        }

    if (cs == 0) {
        const float scale = 1.0f / 128.0f;
        float* obase = out + (((long)bb * 81 + (long)wave * 9) * 128 + y) * 128 + x0;
        #pragma unroll
        for (int q = 0; q < 9; ++q) {
            const float4 v = make_float4(acc[q][0] * scale, acc[q][1] * scale,
                                         acc[q][2] * scale, acc[q][3] * scale);
            *(float4*)(obase + (long)q * plane) = v;
        }
    }
}

extern "C" void kernel_launch(void* const* d_in, const int* in_sizes, int n_in,
                              void* d_out, int out_size, void* d_ws, size_t ws_size,
                              hipStream_t stream) {
    const float* a = (const float*)d_in[0];
    const float* b = (const float*)d_in[1];
    float* out = (float*)d_out;
    // grid: 8 batches * 128 y-rows = 1024 blocks; 576 threads (9 waves, wave = p)
    hipLaunchKernelGGL(corr_kernel, dim3(1024), dim3(576), 0, stream, a, b, out);
}

// Round 2
// 232.502 us; speedup vs baseline: 1.5415x; 1.5415x over previous
//
#include <hip/hip_runtime.h>

// Correlation: out[b, (p+4)*9+(q+4), y, x] = (1/128) * sum_c A[b,c,y,x] * B[b,c,y+p,x+q]
// B zero-padded outside [0,128). A,B = (8,128,128,128) fp32; out = (8,81,128,128) fp32.
//
// R2: latency fix. CC=4 (21.6 KB LDS -> 2 blocks/CU even if pool is 64KB),
// register prefetch double-buffer to hide global latency behind compute,
// pow2 staging index math, one-time zero of padded b_s.

#define CC 4          // channels per LDS chunk
#define BW 136        // padded B row: j = x+4, j in [0,136)

__global__ __launch_bounds__(576, 5)
void corr_kernel(const float* __restrict__ A, const float* __restrict__ B,
                 float* __restrict__ out)
{
    // block -> (batch, y); batch = blockIdx%8 for XCD affinity
    const int bidx = blockIdx.x;
    const int bb = bidx & 7;
    const int y  = bidx >> 3;

    const int tid  = threadIdx.x;
    const int wave = tid >> 6;      // 0..8  -> p = wave-4
    const int lane = tid & 63;
    const int cs   = lane >> 5;     // channel split (0/1)
    const int xt   = lane & 31;
    const int x0   = xt << 2;       // x = x0..x0+3

    __shared__ float a_s[CC][128];
    __shared__ float b_s[9][CC][BW];

    // one-time zero of b_s: pads (j<4, j>=132) and OOB rows stay zero forever
    {
        float4* p = (float4*)&b_s[0][0][0];
        const int total = 9 * CC * BW / 4;   // 1224 float4
        for (int i = tid; i < total; i += 576) p[i] = make_float4(0.f, 0.f, 0.f, 0.f);
    }

    float acc[9][4];
    #pragma unroll
    for (int q = 0; q < 9; ++q)
        #pragma unroll
        for (int i = 0; i < 4; ++i) acc[q][i] = 0.f;

    const long plane = 128L * 128L;
    const float* Abase = A + (long)bb * 128 * plane + (long)y * 128;
    const float* Bbase = B + (long)bb * 128 * plane;

    // B staging map (pow2): row r = tid>>4 (36 rows = 9p x 4c), i = tid&15 -> f4 cols i, i+16
    const int brow = tid >> 4;
    const int bi   = tid & 15;
    const int bpr  = brow >> 2;          // 0..8
    const int bcl  = brow & 3;           // 0..3
    const int bys  = y + bpr - 4;
    const bool bvalid = (unsigned)bys < 128u;
    const float* Brow = Bbase + (long)bys * 128;

    // A staging map: threads < 128: c_l = tid>>5, f4 col = tid&31
    const bool aact = tid < 128;
    const int acl = tid >> 5;
    const int af  = tid & 31;

    float4 pb0 = make_float4(0.f,0.f,0.f,0.f), pb1 = pb0, pa = pb0;

    // prefetch chunk 0
    if (bvalid) {
        const float* src = Brow + (long)bcl * plane;
        pb0 = *(const float4*)(src + (bi << 2));
        pb1 = *(const float4*)(src + ((bi + 16) << 2));
    }
    if (aact) pa = *(const float4*)(Abase + (long)acl * plane + (af << 2));

    __syncthreads();   // zero-init visible before first writes

    for (int ch0 = 0; ch0 < 128; ch0 += CC) {
        // ---- write prefetched regs -> LDS
        if (bvalid) {
            *(float4*)&b_s[bpr][bcl][4 + (bi << 2)]        = pb0;
            *(float4*)&b_s[bpr][bcl][4 + ((bi + 16) << 2)] = pb1;
        }
        if (aact) *(float4*)&a_s[acl][af << 2] = pa;
        __syncthreads();

        // ---- issue next chunk's global loads (overlap with compute below)
        if (ch0 + CC < 128) {
            const int nc = ch0 + CC;
            if (bvalid) {
                const float* src = Brow + (long)(nc + bcl) * plane;
                pb0 = *(const float4*)(src + (bi << 2));
                pb1 = *(const float4*)(src + ((bi + 16) << 2));
            }
            if (aact) pa = *(const float4*)(Abase + (long)(nc + acl) * plane + (af << 2));
        }

        // ---- compute: channels cs and cs+2 of this chunk
        #pragma unroll
        for (int cc = 0; cc < CC / 2; ++cc) {
            const int c_l = (cc << 1) + cs;
            const float4 av = *(const float4*)&a_s[c_l][x0];
            // window j in [x0, x0+11]  (j = x+q+4, x = x0+i)
            const float4 b0 = *(const float4*)&b_s[wave][c_l][x0];
            const float4 b1 = *(const float4*)&b_s[wave][c_l][x0 + 4];
            const float4 b2 = *(const float4*)&b_s[wave][c_l][x0 + 8];
            const float bw[12] = { b0.x, b0.y, b0.z, b0.w,
                                   b1.x, b1.y, b1.z, b1.w,
                                   b2.x, b2.y, b2.z, b2.w };
            const float av4[4] = { av.x, av.y, av.z, av.w };
            #pragma unroll
            for (int q = 0; q < 9; ++q)
                #pragma unroll
                for (int i = 0; i < 4; ++i)
                    acc[q][i] += av4[i] * bw[q + i];
        }
        __syncthreads();
    }

    // ---- combine channel-split halves (lane L += lane L+32)
    #pragma unroll
    for (int q = 0; q < 9; ++q)
        #pragma unroll
        for (int i = 0; i < 4; ++i)
            acc[q][i] += __shfl_down(acc[q][i], 32);

    if (cs == 0) {
        const float scale = 1.0f / 128.0f;
        float* obase = out + (((long)bb * 81 + (long)wave * 9) * 128 + y) * 128 + x0;
        #pragma unroll
        for (int q = 0; q < 9; ++q) {
            const float4 v = make_float4(acc[q][0] * scale, acc[q][1] * scale,
                                         acc[q][2] * scale, acc[q][3] * scale);
            *(float4*)(obase + (long)q * plane) = v;
        }
    }
}

extern "C" void kernel_launch(void* const* d_in, const int* in_sizes, int n_in,
                              void* d_out, int out_size, void* d_ws, size_t ws_size,
                              hipStream_t stream) {
    const float* a = (const float*)d_in[0];
    const float* b = (const float*)d_in[1];
    float* out = (float*)d_out;
    hipLaunchKernelGGL(corr_kernel, dim3(1024), dim3(576), 0, stream, a, b, out);
}